// Round 3
// baseline (649.768 us; speedup 1.0000x reference)
//
#include <hip/hip_runtime.h>
#include <stdint.h>

#define N_TOT 16384
#define BATCH 16
#define LNEI  32
#define DM    256
#define NH    8
#define DH    32
#define DFF   1024

typedef __attribute__((ext_vector_type(8))) short  short8;
typedef __attribute__((ext_vector_type(4))) float  floatx4;

static __device__ __forceinline__ float b2f(unsigned short u) {
  union { unsigned int u; float f; } x; x.u = ((unsigned int)u) << 16; return x.f;
}
static __device__ __forceinline__ unsigned short f2b(float f) {
  union { float f; unsigned int u; } x; x.f = f;
  unsigned int r = x.u + 0x7fffu + ((x.u >> 16) & 1u);
  return (unsigned short)(r >> 16);
}
// load 8 contiguous f32, round to bf16, pack into MFMA fragment
static __device__ __forceinline__ short8 cvt8(const float* p) {
  floatx4 a = *(const floatx4*)p;
  floatx4 b = *(const floatx4*)(p + 4);
  short8 r;
  r[0] = (short)f2b(a[0]); r[1] = (short)f2b(a[1]);
  r[2] = (short)f2b(a[2]); r[3] = (short)f2b(a[3]);
  r[4] = (short)f2b(b[0]); r[5] = (short)f2b(b[1]);
  r[6] = (short)f2b(b[2]); r[7] = (short)f2b(b[3]);
  return r;
}

// C[M,Nd] = A[M,K] @ W[Nd,K]^T + bias (+ A2 @ W2^T + bias2), optional ReLU.
// W is float32 (original weights). A is float32 (AF32) or bf16 ws buffer.
// Wave computes 16(M) x 64(N); block = 4 waves stacked in M -> 64x64 tile.
// A-frag: lane = A[m0+(lane&15)][k0+quad*8 ..+8]; B-frag: W[n0+(lane&15)][same]
// C/D: col = lane&15 (+16*t), row = quad*4 + i.  (verified layouts, m89/m91)
template<bool RELU, bool DUAL, bool AF32>
__global__ __launch_bounds__(256) void gemm_bt(
    const void* __restrict__ Ap, const float* __restrict__ W,
    const float* __restrict__ bias,
    const void* __restrict__ A2p, const float* __restrict__ W2,
    const float* __restrict__ bias2,
    unsigned short* __restrict__ C, int M, int Nd, int K)
{
  const int wave = threadIdx.x >> 6;
  const int lane = threadIdx.x & 63;
  const int quad = lane >> 4;
  const int l16  = lane & 15;
  const int m0 = blockIdx.x * 64 + wave * 16;
  const int n0 = blockIdx.y * 64;

  const float*          arowf = nullptr;
  const unsigned short* arowb = nullptr;
  const float*          a2rowf = nullptr;
  if (AF32) arowf = ((const float*)Ap) + (size_t)(m0 + l16) * K + quad * 8;
  else      arowb = ((const unsigned short*)Ap) + (size_t)(m0 + l16) * K + quad * 8;
  const float* wrow = W + (size_t)(n0 + l16) * K + quad * 8;
  const float* w2row = nullptr;
  if (DUAL) {
    a2rowf = ((const float*)A2p) + (size_t)(m0 + l16) * K + quad * 8;
    w2row  = W2 + (size_t)(n0 + l16) * K + quad * 8;
  }

  floatx4 acc0 = {0.f,0.f,0.f,0.f};
  floatx4 acc1 = acc0, acc2 = acc0, acc3 = acc0;

  for (int k0 = 0; k0 < K; k0 += 32) {
    short8 a;
    if (AF32) a = cvt8(arowf + k0);
    else      a = *(const short8*)(arowb + k0);
    short8 w0 = cvt8(wrow + k0);
    short8 w1 = cvt8(wrow + (size_t)16 * K + k0);
    short8 w2 = cvt8(wrow + (size_t)32 * K + k0);
    short8 w3 = cvt8(wrow + (size_t)48 * K + k0);
    acc0 = __builtin_amdgcn_mfma_f32_16x16x32_bf16(a, w0, acc0, 0, 0, 0);
    acc1 = __builtin_amdgcn_mfma_f32_16x16x32_bf16(a, w1, acc1, 0, 0, 0);
    acc2 = __builtin_amdgcn_mfma_f32_16x16x32_bf16(a, w2, acc2, 0, 0, 0);
    acc3 = __builtin_amdgcn_mfma_f32_16x16x32_bf16(a, w3, acc3, 0, 0, 0);
    if (DUAL) {
      short8 b  = cvt8(a2rowf + k0);
      short8 u0 = cvt8(w2row + k0);
      short8 u1 = cvt8(w2row + (size_t)16 * K + k0);
      short8 u2 = cvt8(w2row + (size_t)32 * K + k0);
      short8 u3 = cvt8(w2row + (size_t)48 * K + k0);
      acc0 = __builtin_amdgcn_mfma_f32_16x16x32_bf16(b, u0, acc0, 0, 0, 0);
      acc1 = __builtin_amdgcn_mfma_f32_16x16x32_bf16(b, u1, acc1, 0, 0, 0);
      acc2 = __builtin_amdgcn_mfma_f32_16x16x32_bf16(b, u2, acc2, 0, 0, 0);
      acc3 = __builtin_amdgcn_mfma_f32_16x16x32_bf16(b, u3, acc3, 0, 0, 0);
    }
  }

  const int col0 = n0 + l16;
  const int row0 = m0 + quad * 4;
  #pragma unroll
  for (int t = 0; t < 4; ++t) {
    floatx4 acc = (t == 0) ? acc0 : (t == 1) ? acc1 : (t == 2) ? acc2 : acc3;
    const int col = col0 + t * 16;
    float bv = bias[col];
    if (DUAL) bv += bias2[col];
    #pragma unroll
    for (int i = 0; i < 4; ++i) {
      float v = acc[i] + bv;
      if (RELU) v = fmaxf(v, 0.f);
      C[(size_t)(row0 + i) * Nd + col] = f2b(v);
    }
  }
}

// One block per query. 256 threads = (h, l) / (h, dh) pairs. q/k/v are bf16 ws.
__global__ __launch_bounds__(256) void attn_kernel(
    const unsigned short* __restrict__ q, const unsigned short* __restrict__ k,
    const unsigned short* __restrict__ v,
    const int* __restrict__ key_batch_cnt, const int* __restrict__ index_pair,
    const int* __restrict__ index_pair_batch,
    unsigned short* __restrict__ out)
{
  const int n = blockIdx.x;
  const int t = threadIdx.x;
  __shared__ int   s_gidx[LNEI];
  __shared__ float s_attn[NH][LNEI];
  __shared__ float s_q[DM];

  s_q[t] = b2f(q[(size_t)n * DM + t]);
  if (t < LNEI) {
    const int b = index_pair_batch[n];
    int off = 0;
    for (int i = 0; i < b; ++i) off += key_batch_cnt[i];
    const int ip = index_pair[(size_t)n * LNEI + t];
    s_gidx[t] = (ip < 0) ? -1 : (ip + off);
  }
  __syncthreads();

  const int h = t >> 5;
  const int l = t & 31;
  const int g = s_gidx[l];
  float score;
  if (g < 0) {
    score = -1e9f;
  } else {
    const unsigned short* krow = k + (size_t)g * DM + h * DH;
    float acc = 0.f;
    #pragma unroll
    for (int j = 0; j < DH; ++j) acc += s_q[h * DH + j] * b2f(krow[j]);
    score = acc * 0.17677669529663687f;  // 32^-0.5
  }
  s_attn[h][l] = score;
  __syncthreads();

  float m = -1e30f;
  #pragma unroll
  for (int j = 0; j < LNEI; ++j) m = fmaxf(m, s_attn[h][j]);
  float sum = 0.f;
  #pragma unroll
  for (int j = 0; j < LNEI; ++j) sum += __expf(s_attn[h][j] - m);
  const float a = __expf(score - m) / sum;
  __syncthreads();
  s_attn[h][l] = a;
  __syncthreads();

  const int dh = t & 31;
  float acc = 0.f;
  #pragma unroll
  for (int j = 0; j < LNEI; ++j) {
    int gj = s_gidx[j];
    if (gj < 0) gj = 0;
    acc += s_attn[h][j] * b2f(v[(size_t)gj * DM + h * DH + dh]);
  }
  out[(size_t)n * DM + t] = f2b(acc);
}

// out = LN(in1 + in2) * g + b. in1 f32 (original input) or bf16 ws; in2 bf16.
// OUTF32: write float32 (final output), else bf16 (ws intermediate).
template<bool IN1F32, bool OUTF32>
__global__ __launch_bounds__(256) void ln_kernel(
    const void* __restrict__ in1, const unsigned short* __restrict__ in2,
    const float* __restrict__ g, const float* __restrict__ b,
    void* __restrict__ out)
{
  const int n = blockIdx.x;
  const int t = threadIdx.x;
  __shared__ float red[DM];

  float a1;
  if (IN1F32) a1 = ((const float*)in1)[(size_t)n * DM + t];
  else        a1 = b2f(((const unsigned short*)in1)[(size_t)n * DM + t]);
  const float a = a1 + b2f(in2[(size_t)n * DM + t]);
  red[t] = a;
  __syncthreads();
  for (int s = 128; s > 0; s >>= 1) {
    if (t < s) red[t] += red[t + s];
    __syncthreads();
  }
  const float mean = red[0] * (1.0f / DM);
  __syncthreads();
  const float d = a - mean;
  red[t] = d * d;
  __syncthreads();
  for (int s = 128; s > 0; s >>= 1) {
    if (t < s) red[t] += red[t + s];
    __syncthreads();
  }
  const float var = red[0] * (1.0f / DM);
  const float y = d * rsqrtf(var + 1e-5f) * g[t] + b[t];
  if (OUTF32) ((float*)out)[(size_t)n * DM + t] = y;
  else        ((unsigned short*)out)[(size_t)n * DM + t] = f2b(y);
}

extern "C" void kernel_launch(void* const* d_in, const int* in_sizes, int n_in,
                              void* d_out, int out_size, void* d_ws, size_t ws_size,
                              hipStream_t stream) {
  const float* tgt  = (const float*)d_in[0];
  const float* mem  = (const float*)d_in[1];
  const float* pos  = (const float*)d_in[2];
  const int* kbc    = (const int*)d_in[3];
  const int* ipair  = (const int*)d_in[4];
  const int* ipb    = (const int*)d_in[5];
  const float* Wq   = (const float*)d_in[6];
  const float* bq   = (const float*)d_in[7];
  const float* Wkc  = (const float*)d_in[8];
  const float* bkc  = (const float*)d_in[9];
  const float* Wkp  = (const float*)d_in[10];
  const float* bkp  = (const float*)d_in[11];
  const float* Wv   = (const float*)d_in[12];
  const float* bv   = (const float*)d_in[13];
  const float* Wo   = (const float*)d_in[14];
  const float* bo   = (const float*)d_in[15];
  const float* W1   = (const float*)d_in[16];
  const float* b1   = (const float*)d_in[17];
  const float* W2   = (const float*)d_in[18];
  const float* b2   = (const float*)d_in[19];
  const float* g2   = (const float*)d_in[20];
  const float* be2  = (const float*)d_in[21];
  const float* g3   = (const float*)d_in[22];
  const float* be3  = (const float*)d_in[23];

  // Compact workspace via lifetime reuse (total 6*NB u16 = 50.3 MB):
  //  [0,NB)=q / later h1[0,4NB)   [NB,2NB)=k   [2NB,3NB)=v   [3NB,4NB)=ao
  //  [4NB,5NB)=t2 / later ff      [5NB,6NB)=x
  const size_t NB = (size_t)N_TOT * DM;
  unsigned short* ws = (unsigned short*)d_ws;
  unsigned short* q_b  = ws;
  unsigned short* k_b  = ws + NB;
  unsigned short* v_b  = ws + 2 * NB;
  unsigned short* ao_b = ws + 3 * NB;
  unsigned short* t2_b = ws + 4 * NB;
  unsigned short* x_b  = ws + 5 * NB;
  unsigned short* h1_b = ws;            // [N, DFF] = 4*NB, q/k/v/ao dead by then
  unsigned short* ff_b = ws + 4 * NB;   // t2 dead by then

  dim3 blk(256);
  dim3 gD(N_TOT / 64, DM / 64);
  dim3 gF(N_TOT / 64, DFF / 64);

  gemm_bt<false, false, true><<<gD, blk, 0, stream>>>(tgt, Wq, bq, nullptr, nullptr, nullptr,
                                                      q_b, N_TOT, DM, DM);
  gemm_bt<false, true, true><<<gD, blk, 0, stream>>>(mem, Wkc, bkc, pos, Wkp, bkp,
                                                     k_b, N_TOT, DM, DM);
  gemm_bt<false, false, true><<<gD, blk, 0, stream>>>(mem, Wv, bv, nullptr, nullptr, nullptr,
                                                      v_b, N_TOT, DM, DM);
  attn_kernel<<<dim3(N_TOT), blk, 0, stream>>>(q_b, k_b, v_b, kbc, ipair, ipb, ao_b);
  gemm_bt<false, false, false><<<gD, blk, 0, stream>>>(ao_b, Wo, bo, nullptr, nullptr, nullptr,
                                                       t2_b, N_TOT, DM, DM);
  ln_kernel<true, false><<<dim3(N_TOT), blk, 0, stream>>>(tgt, t2_b, g2, be2, x_b);
  gemm_bt<true, false, false><<<gF, blk, 0, stream>>>(x_b, W1, b1, nullptr, nullptr, nullptr,
                                                      h1_b, N_TOT, DFF, DM);
  gemm_bt<false, false, false><<<gD, blk, 0, stream>>>(h1_b, W2, b2, nullptr, nullptr, nullptr,
                                                       ff_b, N_TOT, DM, DFF);
  ln_kernel<false, true><<<dim3(N_TOT), blk, 0, stream>>>(x_b, ff_b, g3, be3, d_out);
}

// Round 4
// 302.725 us; speedup vs baseline: 2.1464x; 2.1464x over previous
//
#include <hip/hip_runtime.h>
#include <stdint.h>

#define N_TOT 16384
#define LNEI  32
#define DM    256
#define NH    8
#define DH    32
#define DFF   1024

typedef __attribute__((ext_vector_type(8))) short  short8;
typedef __attribute__((ext_vector_type(4))) float  floatx4;
typedef __attribute__((ext_vector_type(4))) unsigned short ushort4_t;

static __device__ __forceinline__ float b2f(unsigned short u) {
  union { unsigned int u; float f; } x; x.u = ((unsigned int)u) << 16; return x.f;
}
static __device__ __forceinline__ unsigned short f2b(float f) {
  union { float f; unsigned int u; } x; x.f = f;
  unsigned int r = x.u + 0x7fffu + ((x.u >> 16) & 1u);
  return (unsigned short)(r >> 16);
}

// ---------------- conversion pass: f32 -> bf16 into ws (strided dst) --------
#define NSEG 11
struct Seg { const float* src; unsigned short* dst; int cols; int ostride; int ooff; int begin; };
struct SegTable { Seg s[NSEG]; int total; };

__global__ __launch_bounds__(256) void cvt_all(SegTable T) {
  int e = (blockIdx.x * 256 + threadIdx.x) * 4;
  if (e >= T.total) return;
  int si = 0;
  #pragma unroll
  for (int i = 1; i < NSEG; ++i) if (e >= T.s[i].begin) si = i;
  const Seg s = T.s[si];
  const int le = e - s.begin;
  const int row = le / s.cols;
  const int col = le - row * s.cols;
  floatx4 v = *(const floatx4*)(s.src + le);
  ushort4_t o;
  o.x = f2b(v[0]); o.y = f2b(v[1]); o.z = f2b(v[2]); o.w = f2b(v[3]);
  *(ushort4_t*)(s.dst + (size_t)row * s.ostride + s.ooff + col) = o;
}

// ---------------- tiled bf16 GEMM: C = A @ W^T + bias (+bias2), opt ReLU ----
// BM=128, BK=32, BN in {64,128}. LDS staged via global_load_lds width=16
// (wave-uniform LDS base + lane*16, flat row-major tiles, NO padding).
// MFMA 16x16x32 bf16; A-frag lane: A[r=l16][k=quad*8..+8]; C/D: col=l16,
// row=quad*4+i (verified layouts m89/m91).
static __device__ __forceinline__ void gl_lds16(const unsigned short* g, unsigned short* l) {
  __builtin_amdgcn_global_load_lds(
      (const __attribute__((address_space(1))) unsigned int*)g,
      (__attribute__((address_space(3))) unsigned int*)l, 16, 0, 0);
}

template<int BN, bool RELU>
__global__ __launch_bounds__(256) void gemm_tile(
    const unsigned short* __restrict__ A, const unsigned short* __restrict__ W,
    const float* __restrict__ bias, const float* __restrict__ bias2,
    unsigned short* __restrict__ C, int M, int Nd, int K)
{
  constexpr int BM = 128, BK = 32;
  constexpr int MI = (BN == 128) ? 4 : 2;    // 16-row blocks per wave
  constexpr int NI = 4;                      // 16-col blocks per wave
  __shared__ unsigned short sA[BM * BK];
  __shared__ unsigned short sB[BN * BK];

  const int w    = threadIdx.x >> 6;
  const int lane = threadIdx.x & 63;
  const int quad = lane >> 4;
  const int l16  = lane & 15;
  const int m0 = blockIdx.x * BM;
  const int n0 = blockIdx.y * BN;
  const int wrow0 = (BN == 128) ? (w >> 1) * 64 : w * 32;
  const int wcol0 = (BN == 128) ? (w & 1) * 64 : 0;

  // staging source coords (flat = chunk*512 + lane*8; row=flat/32, col=flat%32)
  const int aflat0 = w * 512 + lane * 8;          // chunk c adds c*2048
  const int ar0 = aflat0 >> 5, ac = aflat0 & 31;

  floatx4 acc[MI][NI] = {};

  for (int k0 = 0; k0 < K; k0 += BK) {
    __syncthreads();   // previous iter's LDS reads done before overwrite
    // stage A: 128x32 = 8192B = 8 wave-chunks (2 per wave)
    #pragma unroll
    for (int c = 0; c < 2; ++c) {
      const int row = ar0 + c * 64;                    // (c*2048)/32 = c*64
      gl_lds16(A + (size_t)(m0 + row) * K + k0 + ac, &sA[(c * 4 + w) * 512]);
    }
    // stage B: BN x 32
    if (BN == 128) {
      #pragma unroll
      for (int c = 0; c < 2; ++c) {
        const int row = ar0 + c * 64;
        gl_lds16(W + (size_t)(n0 + row) * K + k0 + ac, &sB[(c * 4 + w) * 512]);
      }
    } else {
      gl_lds16(W + (size_t)(n0 + ar0) * K + k0 + ac, &sB[w * 512]);
    }
    __syncthreads();   // drains vmcnt (global_load_lds) + lgkm

    short8 af[MI], bf[NI];
    #pragma unroll
    for (int mi = 0; mi < MI; ++mi)
      af[mi] = *(const short8*)&sA[(wrow0 + mi * 16 + l16) * BK + quad * 8];
    #pragma unroll
    for (int ni = 0; ni < NI; ++ni)
      bf[ni] = *(const short8*)&sB[(wcol0 + ni * 16 + l16) * BK + quad * 8];
    #pragma unroll
    for (int mi = 0; mi < MI; ++mi)
      #pragma unroll
      for (int ni = 0; ni < NI; ++ni)
        acc[mi][ni] = __builtin_amdgcn_mfma_f32_16x16x32_bf16(af[mi], bf[ni], acc[mi][ni], 0, 0, 0);
  }

  #pragma unroll
  for (int ni = 0; ni < NI; ++ni) {
    const int col = n0 + wcol0 + ni * 16 + l16;
    float bv = bias[col];
    if (bias2) bv += bias2[col];
    #pragma unroll
    for (int mi = 0; mi < MI; ++mi) {
      const int row0 = m0 + wrow0 + mi * 16 + quad * 4;
      #pragma unroll
      for (int i = 0; i < 4; ++i) {
        float v = acc[mi][ni][i] + bv;
        if (RELU) v = fmaxf(v, 0.f);
        C[(size_t)(row0 + i) * Nd + col] = f2b(v);
      }
    }
  }
}

// ---------------- local gather attention: 1 block / query -------------------
__global__ __launch_bounds__(256) void attn_kernel(
    const unsigned short* __restrict__ q, const unsigned short* __restrict__ k,
    const unsigned short* __restrict__ v,
    const int* __restrict__ key_batch_cnt, const int* __restrict__ index_pair,
    const int* __restrict__ index_pair_batch,
    unsigned short* __restrict__ out)
{
  const int n = blockIdx.x;
  const int t = threadIdx.x;
  __shared__ int   s_gidx[LNEI];
  __shared__ float s_attn[NH][LNEI];
  __shared__ float s_q[DM];

  s_q[t] = b2f(q[(size_t)n * DM + t]);
  if (t < LNEI) {
    const int b = index_pair_batch[n];
    int off = 0;
    for (int i = 0; i < b; ++i) off += key_batch_cnt[i];
    const int ip = index_pair[(size_t)n * LNEI + t];
    s_gidx[t] = (ip < 0) ? -1 : (ip + off);
  }
  __syncthreads();

  const int h = t >> 5;
  const int l = t & 31;
  const int g = s_gidx[l];
  float score;
  if (g < 0) {
    score = -1e9f;
  } else {
    const unsigned short* krow = k + (size_t)g * DM + h * DH;
    float acc = 0.f;
    #pragma unroll
    for (int j = 0; j < DH; ++j) acc += s_q[h * DH + j] * b2f(krow[j]);
    score = acc * 0.17677669529663687f;
  }
  s_attn[h][l] = score;
  __syncthreads();

  float m = -1e30f;
  #pragma unroll
  for (int j = 0; j < LNEI; ++j) m = fmaxf(m, s_attn[h][j]);
  float sum = 0.f;
  #pragma unroll
  for (int j = 0; j < LNEI; ++j) sum += __expf(s_attn[h][j] - m);
  const float a = __expf(score - m) / sum;
  __syncthreads();
  s_attn[h][l] = a;
  __syncthreads();

  const int dh = t & 31;
  float acc = 0.f;
  #pragma unroll
  for (int j = 0; j < LNEI; ++j) {
    int gj = s_gidx[j];
    if (gj < 0) gj = 0;
    acc += s_attn[h][j] * b2f(v[(size_t)gj * DM + h * DH + dh]);
  }
  out[(size_t)n * DM + t] = f2b(acc);
}

// ---------------- residual + LayerNorm --------------------------------------
template<bool IN1F32, bool OUTF32>
__global__ __launch_bounds__(256) void ln_kernel(
    const void* __restrict__ in1, const unsigned short* __restrict__ in2,
    const float* __restrict__ g, const float* __restrict__ b,
    void* __restrict__ out)
{
  const int n = blockIdx.x;
  const int t = threadIdx.x;
  __shared__ float red[DM];

  float a1;
  if (IN1F32) a1 = ((const float*)in1)[(size_t)n * DM + t];
  else        a1 = b2f(((const unsigned short*)in1)[(size_t)n * DM + t]);
  const float a = a1 + b2f(in2[(size_t)n * DM + t]);
  red[t] = a;
  __syncthreads();
  for (int s = 128; s > 0; s >>= 1) {
    if (t < s) red[t] += red[t + s];
    __syncthreads();
  }
  const float mean = red[0] * (1.0f / DM);
  __syncthreads();
  const float d = a - mean;
  red[t] = d * d;
  __syncthreads();
  for (int s = 128; s > 0; s >>= 1) {
    if (t < s) red[t] += red[t + s];
    __syncthreads();
  }
  const float var = red[0] * (1.0f / DM);
  const float y = d * rsqrtf(var + 1e-5f) * g[t] + b[t];
  if (OUTF32) ((float*)out)[(size_t)n * DM + t] = y;
  else        ((unsigned short*)out)[(size_t)n * DM + t] = f2b(y);
}

extern "C" void kernel_launch(void* const* d_in, const int* in_sizes, int n_in,
                              void* d_out, int out_size, void* d_ws, size_t ws_size,
                              hipStream_t stream) {
  const float* tgt  = (const float*)d_in[0];
  const float* mem  = (const float*)d_in[1];
  const float* pos  = (const float*)d_in[2];
  const int* kbc    = (const int*)d_in[3];
  const int* ipair  = (const int*)d_in[4];
  const int* ipb    = (const int*)d_in[5];
  const float* Wq   = (const float*)d_in[6];
  const float* bq   = (const float*)d_in[7];
  const float* Wkc  = (const float*)d_in[8];
  const float* bkc  = (const float*)d_in[9];
  const float* Wkp  = (const float*)d_in[10];
  const float* bkp  = (const float*)d_in[11];
  const float* Wv   = (const float*)d_in[12];
  const float* bv   = (const float*)d_in[13];
  const float* Wo   = (const float*)d_in[14];
  const float* bo   = (const float*)d_in[15];
  const float* W1   = (const float*)d_in[16];
  const float* b1   = (const float*)d_in[17];
  const float* W2   = (const float*)d_in[18];
  const float* b2   = (const float*)d_in[19];
  const float* g2   = (const float*)d_in[20];
  const float* be2  = (const float*)d_in[21];
  const float* g3   = (const float*)d_in[22];
  const float* be3  = (const float*)d_in[23];

  // ws layout (u16 elems), lifetime-packed; NB = N*D
  const size_t NB = (size_t)N_TOT * DM;           // 4194304
  unsigned short* ws = (unsigned short*)d_ws;
  unsigned short* tgt_b = ws;                     // dead after q-GEMM
  unsigned short* ao_b  = ws;                     //   reused by attn output
  unsigned short* mem_b = ws + NB;                // dead after v-GEMM
  unsigned short* t2_b  = ws + NB;                //   reused by o-GEMM out
  unsigned short* mp_b  = ws + 2 * NB;            // [N,512] cat(mem,pos); dead after k-GEMM
  unsigned short* x_b   = ws + 2 * NB;            //   reused by ln1 out
  unsigned short* ff_b  = ws + 3 * NB;            //   reused by W2 out
  unsigned short* q_b   = ws + 4 * NB;
  unsigned short* k_b   = ws + 5 * NB;
  unsigned short* v_b   = ws + 6 * NB;
  unsigned short* h1_b  = ws + 4 * NB;            // [N,DFF]=4NB; q/k/v dead by W1
  unsigned short* wgt   = ws + 8 * NB;
  unsigned short* Wq_b = wgt;                     // 65536
  unsigned short* Wk_b = wgt + 65536;             // [256,512] cat = 131072
  unsigned short* Wv_b = wgt + 65536 + 131072;
  unsigned short* Wo_b = wgt + 2 * 65536 + 131072;
  unsigned short* W1_b = wgt + 3 * 65536 + 131072; // 262144
  unsigned short* W2_b = wgt + 3 * 65536 + 131072 + 262144;

  // conversion segment table
  SegTable T;
  int beg = 0, i = 0;
  auto seg = [&](const float* s, unsigned short* d, int cols, int ostride, int ooff, int nelem) {
    T.s[i].src = s; T.s[i].dst = d; T.s[i].cols = cols;
    T.s[i].ostride = ostride; T.s[i].ooff = ooff; T.s[i].begin = beg;
    beg += nelem; ++i;
  };
  seg(tgt, tgt_b, DM, DM, 0,   (int)NB);
  seg(mem, mem_b, DM, DM, 0,   (int)NB);
  seg(mem, mp_b,  DM, 512, 0,  (int)NB);
  seg(pos, mp_b,  DM, 512, DM, (int)NB);
  seg(Wq,  Wq_b,  DM, DM, 0,   65536);
  seg(Wkc, Wk_b,  DM, 512, 0,  65536);
  seg(Wkp, Wk_b,  DM, 512, DM, 65536);
  seg(Wv,  Wv_b,  DM, DM, 0,   65536);
  seg(Wo,  Wo_b,  DM, DM, 0,   65536);
  seg(W1,  W1_b,  DM, DM, 0,   262144);
  seg(W2,  W2_b,  DFF, DFF, 0, 262144);
  T.total = beg;

  dim3 blk(256);
  cvt_all<<<dim3((T.total / 4 + 255) / 256), blk, 0, stream>>>(T);

  dim3 gP(N_TOT / 128, DM / 64);    // projections: BN=64 -> 512 blocks
  dim3 gF(N_TOT / 128, DFF / 128);  // W1: BN=128 -> 1024 blocks

  gemm_tile<64, false><<<gP, blk, 0, stream>>>(tgt_b, Wq_b, bq, nullptr, q_b, N_TOT, DM, DM);
  gemm_tile<64, false><<<gP, blk, 0, stream>>>(mp_b, Wk_b, bkc, bkp, k_b, N_TOT, DM, 512);
  gemm_tile<64, false><<<gP, blk, 0, stream>>>(mem_b, Wv_b, bv, nullptr, v_b, N_TOT, DM, DM);
  attn_kernel<<<dim3(N_TOT), blk, 0, stream>>>(q_b, k_b, v_b, kbc, ipair, ipb, ao_b);
  gemm_tile<64, false><<<gP, blk, 0, stream>>>(ao_b, Wo_b, bo, nullptr, t2_b, N_TOT, DM, DM);
  ln_kernel<true, false><<<dim3(N_TOT), blk, 0, stream>>>(tgt, t2_b, g2, be2, x_b);
  gemm_tile<128, true><<<gF, blk, 0, stream>>>(x_b, W1_b, b1, nullptr, h1_b, N_TOT, DFF, DM);
  gemm_tile<64, false><<<gP, blk, 0, stream>>>(h1_b, W2_b, b2, nullptr, ff_b, N_TOT, DM, DFF);
  ln_kernel<false, true><<<dim3(N_TOT), blk, 0, stream>>>(x_b, ff_b, g3, be3, d_out);
}